// Round 3
// baseline (180.299 us; speedup 1.0000x reference)
//
#include <hip/hip_runtime.h>
#include <stdint.h>

#define B_ 32
#define E_ 256
#define L_ 2048
#define D_ 256

#define BE 128             // e-rows per block
#define BD 256             // d-cols per block (full D)
#define BK 32              // k per inner step
#define KS 4               // k-split factor
#define KCHUNK (L_ / KS)   // 512
#define NKT (KCHUNK / BK)  // 16 k-steps per block
#define SUP 128            // k per A super-tile (4 inner steps)

typedef __attribute__((ext_vector_type(2))) float  f32x2;
typedef __attribute__((ext_vector_type(4))) float  f32x4;
typedef __attribute__((ext_vector_type(4))) short  s16x4;
typedef __attribute__((ext_vector_type(8))) short  s16x8;

// B-side row key (unchanged, harness-verified in rounds 1-2).
#define KEYB(row) (((row) >> 1) & 7)

// fp32 -> (hi, lo) bf16 pair. hi = truncated bf16(x); lo = bf16(x - hi).
__device__ __forceinline__ void cvt_hilo1(float x, short &h, short &l) {
    unsigned u = __builtin_bit_cast(unsigned, x);
    h = (short)(u >> 16);
    float hf = __builtin_bit_cast(float, u & 0xFFFF0000u);
    unsigned r = __builtin_bit_cast(unsigned, x - hf);
    l = (short)(r >> 16);
}

__global__ void zero_out_kernel(f32x4* __restrict__ out) {
    out[(size_t)blockIdx.x * 256 + threadIdx.x] = f32x4{0.f, 0.f, 0.f, 0.f};
}

// ---- A super-tile: fetch 128 rows x 512B-contiguous-per-row (2 rows/wave-instr) ----
#define LOAD_A(RA, SS)                                                         \
    {                                                                          \
        _Pragma("unroll")                                                      \
        for (int rr = 0; rr < 8; ++rr)                                         \
            RA[rr] = *(const f32x4*)(Ag + (size_t)(rr * 16 + a_sr) * L_ + (SS) * SUP + a_sc * 4); \
    }

// convert + write the A super-tile (row&7 key is a_sr&7: rr*16 preserves low 3 bits)
#define WRITE_A(RA)                                                            \
    {                                                                          \
        _Pragma("unroll")                                                      \
        for (int rr = 0; rr < 8; ++rr) {                                       \
            s16x4 h, l;                                                        \
            _Pragma("unroll")                                                  \
            for (int i = 0; i < 4; ++i) { short hh, ll; cvt_hilo1(RA[rr][i], hh, ll); h[i] = hh; l[i] = ll; } \
            *(s16x4*)&A_hi[awoff + rr * 2048] = h;                             \
            *(s16x4*)&A_lo[awoff + rr * 2048] = l;                             \
        }                                                                      \
    }

// ---- B (doc): per-step register prefetch (contiguous 32KB/step per block) ----
#define LOADT_B(PB, K0)                                                        \
    {                                                                          \
        _Pragma("unroll")                                                      \
        for (int j = 0; j < 8; ++j)                                            \
            PB[j] = *(const f32x2*)(Sg + (size_t)((K0) + kb * 8 + j) * D_ + dp * 2); \
    }

#define STAGE_B(BbN, PB)                                                       \
    {                                                                          \
        _Pragma("unroll")                                                      \
        for (int dd = 0; dd < 2; ++dd) {                                       \
            s16x8 h, l;                                                        \
            _Pragma("unroll")                                                  \
            for (int j = 0; j < 8; ++j) { short hh, ll; cvt_hilo1(PB[j][dd], hh, ll); h[j] = hh; l[j] = ll; } \
            *(s16x8*)&(BbN)[bwo_h[dd]] = h;                                    \
            *(s16x8*)&(BbN)[bwo_l[dd]] = l;                                    \
        }                                                                      \
    }

// lgkm-only drain + raw barrier: LDS writes visible, global loads stay in flight.
#define LGKM_BARRIER()                                                         \
    {                                                                          \
        asm volatile("s_waitcnt lgkmcnt(0)" ::: "memory");                     \
        __builtin_amdgcn_s_barrier();                                          \
        asm volatile("" ::: "memory");                                         \
    }

// ---- one inner k-step: frag reads -> stage B(k+1) -> issue B loads(k+3) ->
//      MFMA -> lgkm barrier.  S = step index within super (0..3, literal) ----
#define ITER(K, S, BbC, BbN, PB)                                               \
    {                                                                          \
        s16x8 bh[4], bl[4], ah[4], al[4];                                      \
        _Pragma("unroll")                                                      \
        for (int ni = 0; ni < 4; ++ni) {                                       \
            bh[ni] = *(const s16x8*)&(BbC)[bro_h[ni]];                         \
            bl[ni] = *(const s16x8*)&(BbC)[bro_l[ni]];                         \
        }                                                                      \
        _Pragma("unroll")                                                      \
        for (int mi = 0; mi < 4; ++mi) {                                       \
            const int aoff = abase[mi] + ((((S) * 4 + kg) ^ akey[mi]) << 3);   \
            ah[mi] = *(const s16x8*)&A_hi[aoff];                               \
            al[mi] = *(const s16x8*)&A_lo[aoff];                               \
        }                                                                      \
        if ((K) + 1 < NKT) {                                                   \
            STAGE_B(BbN, PB)                                                   \
            if ((K) + 3 < NKT) LOADT_B(PB, ((K) + 3) * BK)                     \
        }                                                                      \
        __builtin_amdgcn_s_setprio(1);                                         \
        _Pragma("unroll")                                                      \
        for (int mi = 0; mi < 4; ++mi)                                         \
            _Pragma("unroll")                                                  \
            for (int ni = 0; ni < 4; ++ni) {                                   \
                acc[mi][ni] = __builtin_amdgcn_mfma_f32_16x16x32_bf16(ah[mi], bh[ni], acc[mi][ni], 0, 0, 0); \
                acc[mi][ni] = __builtin_amdgcn_mfma_f32_16x16x32_bf16(ah[mi], bl[ni], acc[mi][ni], 0, 0, 0); \
                acc[mi][ni] = __builtin_amdgcn_mfma_f32_16x16x32_bf16(al[mi], bh[ni], acc[mi][ni], 0, 0, 0); \
            }                                                                  \
        __builtin_amdgcn_s_setprio(0);                                         \
        if ((K) + 1 < NKT) LGKM_BARRIER()                                      \
    }

__global__ __launch_bounds__(512, 2)
void mean_pool_kernel(const float* __restrict__ doc,
                      const float* __restrict__ emap,
                      const float* __restrict__ lens,
                      float* __restrict__ out) {
    // A super-tile: [128 e-rows][128 k] bf16 hi/lo, 16B chunks XOR-swizzled by row&7.
    __shared__ __align__(16) short A_hi[BE * SUP];      // 32 KB
    __shared__ __align__(16) short A_lo[BE * SUP];      // 32 KB
    __shared__ __align__(16) short Bs[2][BD][64];       // 64 KB (dbuf, round-1/2 layout)
    __shared__ float lens_s[BE];

    const int t  = threadIdx.x;
    const int bi = blockIdx.x;
    // XCD-pairing remap: the two blocks sharing a doc chunk (same b,ks; e0 in {0,1})
    // get the same bi%8 residue -> same XCD L2.  Bijective over 0..255.
    const int r   = bi & 7;
    const int q   = bi >> 3;
    const int ks  = r & 3;
    const int b   = (q >> 1) * 2 + (r >> 2);
    const int e0  = (q & 1) * BE;

    const float* Ag = emap + ((size_t)b * E_ + e0) * L_ + ks * KCHUNK;
    const float* Sg = doc  + (size_t)b * L_ * D_ + (size_t)ks * KCHUNK * D_;

    if (t < BE) lens_s[t] = lens[b * E_ + e0 + t];

    // ---- A super-tile staging coords: 32 lanes/row -> 512B contiguous per row ----
    const int a_sr = t >> 5;     // row within 16-row round
    const int a_sc = t & 31;     // k-quad within 128-k range
    const int akey_w = a_sr & 7; // rr*16 keeps low 3 bits of row == a_sr&7
    const int awoff = a_sr * SUP + (((a_sc >> 1) ^ akey_w) << 3) + (a_sc & 1) * 4;

    // ---- B staging coords (unchanged) ----
    const int dp = t & 127;      // d-pair index
    const int kb = t >> 7;       // k-octet 0..3

    // ---- wave/MFMA coords: 8 waves as 2(e) x 4(d), wave tile 64x64 ----
    const int lane = t & 63;
    const int w    = t >> 6;
    const int eo   = (w & 1) * 64;
    const int dq   = (w >> 1) * 32 * 2;  // (w>>1)*64
    const int ml   = lane & 15;
    const int kg   = lane >> 4;

    // ---- precomputed LDS offsets ----
    int bwo_h[2], bwo_l[2];
    #pragma unroll
    for (int dd = 0; dd < 2; ++dd) {
        const int row = dp * 2 + dd, k = KEYB(row);
        bwo_h[dd] = row * 64 + (((kb    ) ^ k) << 3);
        bwo_l[dd] = row * 64 + (((kb | 4) ^ k) << 3);
    }
    int abase[4], akey[4], bro_h[4], bro_l[4];
    #pragma unroll
    for (int i = 0; i < 4; ++i) {
        const int ar = eo + i * 16 + ml;
        abase[i] = ar * SUP;
        akey[i]  = ar & 7;
        const int br = dq + i * 16 + ml, kB = KEYB(br);
        bro_h[i] = br * 64 + (((kg    ) ^ kB) << 3);
        bro_l[i] = br * 64 + (((kg | 4) ^ kB) << 3);
    }

    f32x4 acc[4][4] = {};
    f32x4 ra[8];                 // A super-tile prefetch (1 super ahead)
    f32x2 pbE[8], pbO[8];        // B 2-deep prefetch

    // ---- prologue ----
    LOAD_A(ra, 0)
    LOADT_B(pbE, 0)
    LOADT_B(pbO, BK)
    STAGE_B((&Bs[0][0][0]), pbE)     // tile 0 -> buf0 (counted vmcnt)
    LOADT_B(pbE, 2 * BK)             // tile 2

    for (int ss = 0; ss < 4; ++ss) {
        // previous super's last barrier guarantees all A-frag reads done
        WRITE_A(ra)                              // counted vmcnt wait on ra
        if (ss < 3) LOAD_A(ra, ss + 1)           // next super's stream, in flight
        LGKM_BARRIER()                           // A (+ pending B) writes visible

        const int kt = ss * 4;
        ITER(kt + 0, 0, (&Bs[0][0][0]), (&Bs[1][0][0]), pbO)
        ITER(kt + 1, 1, (&Bs[1][0][0]), (&Bs[0][0][0]), pbE)
        ITER(kt + 2, 2, (&Bs[0][0][0]), (&Bs[1][0][0]), pbO)
        ITER(kt + 3, 3, (&Bs[1][0][0]), (&Bs[0][0][0]), pbE)
    }

    // ---- epilogue: divide by entity_lens, accumulate k-split partials ----
    #pragma unroll
    for (int mi = 0; mi < 4; ++mi) {
        #pragma unroll
        for (int rr = 0; rr < 4; ++rr) {
            const int er = eo + mi * 16 + kg * 4 + rr;
            const float lv = lens_s[er];
            #pragma unroll
            for (int ni = 0; ni < 4; ++ni)
                atomicAdd(&out[((size_t)(b * E_ + e0 + er)) * D_ + dq + ni * 16 + ml],
                          acc[mi][ni][rr] / lv);
        }
    }
}

extern "C" void kernel_launch(void* const* d_in, const int* in_sizes, int n_in,
                              void* d_out, int out_size, void* d_ws, size_t ws_size,
                              hipStream_t stream) {
    const float* doc  = (const float*)d_in[0];   // [32][2048][256]
    const float* emap = (const float*)d_in[1];   // [32][256][2048]
    const float* lens = (const float*)d_in[2];   // [32][256]
    float* out = (float*)d_out;                  // [32][256][256]

    // zero the output (harness poisons it), then accumulate partials
    zero_out_kernel<<<dim3(out_size / (4 * 256)), dim3(256), 0, stream>>>((f32x4*)out);

    dim3 grid(B_ * (E_ / BE) * (D_ / BD) * KS);  // 256 workgroups, 1 per CU
    dim3 block(512);
    hipLaunchKernelGGL(mean_pool_kernel, grid, block, 0, stream,
                       doc, emap, lens, out);
}